// Round 10
// baseline (69.109 us; speedup 1.0000x reference)
//
#include <hip/hip_runtime.h>
#include <hip/hip_bf16.h>
#include <stdint.h>

// C[4096,10532] = inputs[4096,256] @ concat(lut,queue)[10532,256]^T  (fp32 out)
// R10: WIDE tile BM=32 x BN=512 (BK=64). Purpose: each block's C-row segment
// becomes 2 KB contiguous (vs 512 B at 128x128) -> DRAM page-level write
// efficiency. Theory: all six prior schedule variants were null because the
// store stream (172 MB in 512-B bursts at 42-KB stride) runs at ~3.2 TB/s
// effective; NT(64B)=1.46, sequential=6.7 TB/s bracket it. Waves: all 4 share
// the 32 rows (A-frag LDS broadcast), each owns 128 cols. bm-fast XCD order
// keeps the 262-KB B-tile L2-resident. Swizzle identical to R6 (row&7==lr&7).

#define M_DIM 4096
#define K_DIM 256
#define N_LUT 5532
#define N_Q   5000
#define N_DIM (N_LUT + N_Q)   // 10532
#define BM    32
#define BN    512
#define NT_M  128             // 4096/32
#define NT_N  21              // ceil(10532/512)
#define N_PAD (NT_N * 512)    // 10752

typedef _Float16 f16x8 __attribute__((ext_vector_type(8)));
typedef float f32x4 __attribute__((ext_vector_type(4)));

__device__ __forceinline__ unsigned short f2h(float f) {
  union { _Float16 h; unsigned short u; } v;
  v.h = (_Float16)f;   // v_cvt_f16_f32, RNE
  return v.u;
}

// ---------------- convert fp32 -> f16 into workspace ----------------
__global__ __launch_bounds__(256) void convert_kernel(
    const float* __restrict__ inp, const float* __restrict__ lut,
    const float* __restrict__ que, unsigned short* __restrict__ Abf,
    unsigned short* __restrict__ Bbf) {
  const int AV = M_DIM * K_DIM / 4;  // 262144 float4s for A
  int i = blockIdx.x * 256 + threadIdx.x;  // grid sized exactly
  float4 x;
  unsigned short* dst;
  if (i < AV) {
    x = ((const float4*)inp)[i];
    dst = Abf + i * 4;
  } else {
    int e = (i - AV) * 4;          // element index in padded B
    int row = e >> 8;              // /256
    int col = e & 255;
    if (row < N_LUT)
      x = *(const float4*)(lut + (size_t)row * K_DIM + col);
    else if (row < N_DIM)
      x = *(const float4*)(que + (size_t)(row - N_LUT) * K_DIM + col);
    else
      x = make_float4(0.f, 0.f, 0.f, 0.f);
    dst = Bbf + e;
  }
  ushort4 o;
  o.x = f2h(x.x); o.y = f2h(x.y); o.z = f2h(x.z); o.w = f2h(x.w);
  *(ushort4*)dst = o;
}

// ---------------- GEMM: C = A * B^T, both [rows][K] f16 ----------------
#define GLDS16(gsrc, ldst)                                                  \
  __builtin_amdgcn_global_load_lds(                                         \
      (__attribute__((address_space(1))) void*)(gsrc),                      \
      (__attribute__((address_space(3))) void*)(ldst), 16, 0, 0)

__global__ __launch_bounds__(256, 2) void gemm_kernel(
    const unsigned short* __restrict__ A, const unsigned short* __restrict__ B,
    float* __restrict__ C) {
  // single-buffered tiles: A 32x64 f16 = 4 KB, B 512x64 f16 = 64 KB -> 68 KB
  __shared__ __align__(16) unsigned short As[32 * 64];
  __shared__ __align__(16) unsigned short Bs[512 * 64];

  const int t = threadIdx.x;
  const int lane = t & 63;
  const int wave = t >> 6;         // 4 waves; wave wn owns cols wn*128..+128
  const int wn = wave;

  // grid = 2688 = 8 * 336. XCD chunking, bm-FAST within: consecutive wg in a
  // chunk share the same B-tile (262 KB, L2-resident) across 128 bm values.
  const int nwg = NT_M * NT_N;     // 2688
  const int cpx = nwg >> 3;        // 336
  int bid = blockIdx.x;
  int wg = (bid & 7) * cpx + (bid >> 3);
  const int bm = wg & 127;         // bm-fast (NT_M = 128)
  const int bn = wg >> 7;          // 0..20
  const int brow = bm * BM;
  const int bcol = bn * BN;

  // staging with PRE-SWIZZLED global source (LDS dest linear):
  // lds[row][ch] = global[row][ch ^ (row&7)]  (16B chunks, 8 per 128-B row)
  const int trow = t >> 3;                       // 0..31
  const int tcs = (((t & 7) ^ (trow & 7)) * 8);  // swizzled col, elements
  const unsigned short* gaBase = A + (size_t)(brow + trow) * K_DIM + tcs;
  const unsigned short* gbBase = B + (size_t)(bcol + trow) * K_DIM + tcs;
  const int ldsOff = wave * 512;   // elements; HW adds lane*16 bytes

  // A tile: 32 rows = one issue-round; B tile: 512 rows = 16 issue-rounds
#define STAGE(kt)                                                            \
  do {                                                                       \
    GLDS16(gaBase + (kt) * 64, As + ldsOff);                                 \
    _Pragma("unroll") for (int is = 0; is < 16; ++is) {                      \
      GLDS16(gbBase + (size_t)is * 32 * K_DIM + (kt) * 64,                   \
             Bs + is * 2048 + ldsOff);                                       \
    }                                                                        \
  } while (0)

  f32x4 acc[2][8] = {};
  const int lr = lane & 15;
  const int rsw = lane & 7;        // = row&7 for all fragment rows
  const int cq = lane >> 4;        // quarter-wave id = base col chunk
  const int cc4 = cq * 4;

#pragma unroll
  for (int kt = 0; kt < 4; ++kt) { // K = 256 = 4 * 64
    STAGE(kt);
    __syncthreads();               // vmcnt(0)+lgkmcnt(0) drain + barrier

#pragma unroll
    for (int kk = 0; kk < 64; kk += 32) {
      const int ch = ((kk >> 3) + cq) ^ rsw;   // swizzled 16B chunk, 0..7
      f16x8 a[2], b[8];
#pragma unroll
      for (int i = 0; i < 2; ++i)  // all 4 waves read same A rows: broadcast
        a[i] = *(const f16x8*)&As[(i * 16 + lr) * 64 + ch * 8];
#pragma unroll
      for (int j = 0; j < 8; ++j)
        b[j] = *(const f16x8*)&Bs[(wn * 128 + j * 16 + lr) * 64 + ch * 8];
      // swapped operands: C-row = i*16+lr, C-cols = j*16 + cq*4 + reg
#pragma unroll
      for (int i = 0; i < 2; ++i)
#pragma unroll
        for (int j = 0; j < 8; ++j)
          acc[i][j] = __builtin_amdgcn_mfma_f32_16x16x32_f16(b[j], a[i],
                                                             acc[i][j], 0, 0, 0);
    }
    __syncthreads();               // all waves done reading before next STAGE
  }

  // epilogue: per block-row, waves jointly cover 512*4B = 2 KB contiguous
  const int wcol = bcol + wn * 128;
#pragma unroll
  for (int i = 0; i < 2; ++i) {
    size_t rowBase = (size_t)(brow + i * 16 + lr) * N_DIM;
#pragma unroll
    for (int j = 0; j < 8; ++j) {
      int col = wcol + j * 16 + cc4;
      if (col < N_DIM)             // N_DIM%4==0: f32x4 granule fully valid
        *(f32x4*)&C[rowBase + col] = acc[i][j];
    }
  }
#undef STAGE
}

extern "C" void kernel_launch(void* const* d_in, const int* in_sizes, int n_in,
                              void* d_out, int out_size, void* d_ws, size_t ws_size,
                              hipStream_t stream) {
  const float* inp = (const float*)d_in[0];   // inputs [4096,256]
  // d_in[1] targets, d_in[2] gt_flag: unused by the forward similarity
  const float* lut = (const float*)d_in[3];   // [5532,256]
  const float* que = (const float*)d_in[4];   // [5000,256]
  float* C = (float*)d_out;                   // [4096,10532]

  unsigned short* Abf = (unsigned short*)d_ws;
  unsigned short* Bbf = Abf + (size_t)M_DIM * K_DIM;  // ~7.6 MB of ws

  // (4096*256 + 10752*256) elems / 4 / 256 = 3712 blocks exact
  const int conv_blocks = (M_DIM * K_DIM / 4 + N_PAD * K_DIM / 4) / 256;
  convert_kernel<<<conv_blocks, 256, 0, stream>>>(inp, lut, que, Abf, Bbf);

  gemm_kernel<<<NT_M * NT_N, 256, 0, stream>>>(Abf, Bbf, C);
}